// Round 1
// baseline (871.386 us; speedup 1.0000x reference)
//
#include <hip/hip_runtime.h>
#include <cstdint>
#include <cstddef>

// ---- fixed problem shape ----
constexpr int kB    = 4;
constexpr int kL    = 2048;
constexpr int kH    = 32;
constexpr int kP    = 64;
constexpr int kN    = 32;
constexpr int kD    = 2048;      // d_model
constexpr int kProjW = 4192;
constexpr int kLdp  = 4224;      // padded proj width = 33*128
constexpr int kM    = kB * kL;   // 8192
constexpr int kK    = kD;        // 2048
constexpr int kLC   = 128;       // scan chunk length
constexpr int kNC   = kL / kLC;  // 16

typedef _Float16 f16x8 __attribute__((ext_vector_type(8)));
typedef f16x8 f16x8_t;
typedef float f32x4 __attribute__((ext_vector_type(4)));

__device__ __forceinline__ float lane_bcast(float v, int lane) {
    return __int_as_float(__builtin_amdgcn_readlane(__float_as_int(v), lane));
}
__device__ __forceinline__ float silu_f(float x) { return x / (1.f + __expf(-x)); }

__device__ __forceinline__ void async_copy16(const void* g, void* lds) {
    __builtin_amdgcn_global_load_lds(
        (const __attribute__((address_space(1))) unsigned int*)(uintptr_t)g,
        (__attribute__((address_space(3))) unsigned int*)(uintptr_t)lds,
        16, 0, 0);
}

// ---------------- cast fp32 -> fp16 (8 elems/thread) ----------------
__global__ __launch_bounds__(256) void cast_f16_kernel(const float* __restrict__ in,
                                                       _Float16* __restrict__ out) {
    size_t i = ((size_t)blockIdx.x * 256 + threadIdx.x) * 8;
    float4 a = *(const float4*)(in + i);
    float4 b = *(const float4*)(in + i + 4);
    f16x8 o;
    o[0] = (_Float16)a.x; o[1] = (_Float16)a.y; o[2] = (_Float16)a.z; o[3] = (_Float16)a.w;
    o[4] = (_Float16)b.x; o[5] = (_Float16)b.y; o[6] = (_Float16)b.z; o[7] = (_Float16)b.w;
    *(f16x8*)(out + i) = o;
}

// ------------- transpose + cast: W (R x C fp32) -> Wt (Cpad x R f16), zero pad -------------
__global__ __launch_bounds__(256) void transpose_cast_kernel(const float* __restrict__ W,
                                                             _Float16* __restrict__ Wt,
                                                             int R, int C) {
    __shared__ float tile[32][33];
    const int c0 = blockIdx.x * 32;
    const int r0 = blockIdx.y * 32;
    const int tx = threadIdx.x & 31;
    const int ty = threadIdx.x >> 5;   // 0..7
    #pragma unroll
    for (int i = 0; i < 32; i += 8) {
        int rr = r0 + ty + i;
        int cc = c0 + tx;
        tile[ty + i][tx] = (cc < C) ? W[(size_t)rr * C + cc] : 0.f;
    }
    __syncthreads();
    #pragma unroll
    for (int i = 0; i < 32; i += 8) {
        int cc = c0 + ty + i;          // row in Wt
        int rr = r0 + tx;              // col in Wt
        Wt[(size_t)cc * R + rr] = (_Float16)tile[tx][ty + i];
    }
}

// ---------------- GEMM: C[M x N] = A[M x K] * Bt[N x K]^T (+bias) ----------------
// 128x128 tile, BK=32, 256 threads (4 waves), 16x16x32 f16 MFMA, fragment-ordered LDS
// staged via global_load_lds (16B/lane). OUT_F16: store f16 (ldc elems), else fp32.
// dtside (optional): fp32 copy of cols [4160,4192) -> dtside[row*32 + col-4160].
template <bool OUT_F16>
__global__ __launch_bounds__(256) void gemm_bt_kernel(
    const _Float16* __restrict__ A, const _Float16* __restrict__ Bt,
    const float* __restrict__ bias, int nbias,
    void* __restrict__ Cout, int K, int ldc, float* __restrict__ dtside)
{
    __shared__ __attribute__((aligned(16))) _Float16 As[128 * 32]; // 8 groups of 512
    __shared__ __attribute__((aligned(16))) _Float16 Bs[128 * 32];

    const int tid = threadIdx.x;
    const int w   = tid >> 6;
    const int l   = tid & 63;
    const int r   = l & 15;
    const int q   = l >> 4;
    const size_t tileM = (size_t)blockIdx.y * 128;
    const size_t tileN = (size_t)blockIdx.x * 128;
    const int wr = w >> 1, wc = w & 1;

    const _Float16* ga0 = A  + (tileM + (size_t)(w * 16 + r)) * K + q * 8;
    const _Float16* ga1 = A  + (tileM + (size_t)((w + 4) * 16 + r)) * K + q * 8;
    const _Float16* gb0 = Bt + (tileN + (size_t)(w * 16 + r)) * K + q * 8;
    const _Float16* gb1 = Bt + (tileN + (size_t)((w + 4) * 16 + r)) * K + q * 8;
    _Float16* lA0 = &As[(w) * 512];
    _Float16* lA1 = &As[(w + 4) * 512];
    _Float16* lB0 = &Bs[(w) * 512];
    _Float16* lB1 = &Bs[(w + 4) * 512];

    f32x4 acc[4][4] = {};

    for (int k0 = 0; k0 < K; k0 += 32) {
        async_copy16(ga0 + k0, lA0);
        async_copy16(ga1 + k0, lA1);
        async_copy16(gb0 + k0, lB0);
        async_copy16(gb1 + k0, lB1);
        __syncthreads();
        f16x8 af[4], bfr[4];
        #pragma unroll
        for (int i = 0; i < 4; ++i)
            af[i] = *(const f16x8*)&As[(wr * 4 + i) * 512 + l * 8];
        #pragma unroll
        for (int j = 0; j < 4; ++j)
            bfr[j] = *(const f16x8*)&Bs[(wc * 4 + j) * 512 + l * 8];
        #pragma unroll
        for (int i = 0; i < 4; ++i)
            #pragma unroll
            for (int j = 0; j < 4; ++j)
                acc[i][j] = __builtin_amdgcn_mfma_f32_16x16x32_f16(af[i], bfr[j], acc[i][j], 0, 0, 0);
        __syncthreads();
    }

    #pragma unroll
    for (int j = 0; j < 4; ++j) {
        const int col = (int)tileN + wc * 64 + j * 16 + r;
        float bv = 0.f;
        if (bias != nullptr && col < nbias) bv = bias[col];
        #pragma unroll
        for (int i = 0; i < 4; ++i) {
            const size_t row = tileM + (size_t)(wr * 64 + i * 16 + q * 4);
            #pragma unroll
            for (int u = 0; u < 4; ++u) {
                float v = acc[i][j][u] + bv;
                if (OUT_F16) ((_Float16*)Cout)[(row + u) * ldc + col] = (_Float16)v;
                else         ((float*)Cout)[(row + u) * ldc + col] = v;
                if (dtside != nullptr && col >= 4160 && col < 4192)
                    dtside[(row + u) * 32 + (col - 4160)] = v;
            }
        }
    }
}

// ---------------- dt / dA precompute ----------------
__global__ __launch_bounds__(256) void dt_da_kernel(
    const float* __restrict__ dtraw, const float* __restrict__ A_log,
    const float* __restrict__ dt_bias, float* __restrict__ dtv, float* __restrict__ dAv)
{
    int idx = blockIdx.x * 256 + threadIdx.x;  // (b,h,t) t-minor
    int t  = idx & (kL - 1);
    int bh = idx >> 11;
    int h  = bh & (kH - 1);
    int b  = bh >> 5;
    float z  = dtraw[((size_t)(b * kL + t)) * kH + h] + dt_bias[h];
    float dt = (z > 20.f) ? z : log1pf(expf(z));
    float dA = expf(dt * -expf(A_log[h]));
    dtv[idx] = dt;
    dAv[idx] = dA;
}

// ---------------- scan pass 1: per-chunk local states (zero init) + decay product --------
__global__ __launch_bounds__(64) void scan_pass1_kernel(
    const _Float16* __restrict__ projh, const float* __restrict__ conv_w,
    const float* __restrict__ conv_b, const float* __restrict__ dtv,
    const float* __restrict__ dAv, float* __restrict__ cstate, float* __restrict__ Pch)
{
    const int blk = blockIdx.x;
    const int c   = blk & (kNC - 1);
    const int bh  = blk >> 4;
    const int h   = bh & (kH - 1);
    const int b   = bh >> 5;
    const int l   = threadIdx.x;
    const int t0  = c * kLC;

    const int chx = h * kP + l;          // x conv channel
    const int chb = 2048 + (l & 31);     // B conv channel (duplicated over half-wave)
    const float xw0 = conv_w[chx*4+0], xw1 = conv_w[chx*4+1], xw2 = conv_w[chx*4+2], xw3 = conv_w[chx*4+3];
    const float xbb = conv_b[chx];
    const float bw0 = conv_w[chb*4+0], bw1 = conv_w[chb*4+1], bw2 = conv_w[chb*4+2], bw3 = conv_w[chb*4+3];
    const float bbb = conv_b[chb];

    const _Float16* pb = projh + (size_t)b * kL * kLdp;
    const int colx = 2048 + chx;
    const int colb = 2048 + chb;

    float xq0=0.f, xq1=0.f, xq2=0.f, bq0=0.f, bq1=0.f, bq2=0.f;
    if (c > 0) {
        xq0 = (float)pb[(size_t)(t0-3)*kLdp + colx];
        xq1 = (float)pb[(size_t)(t0-2)*kLdp + colx];
        xq2 = (float)pb[(size_t)(t0-1)*kLdp + colx];
        bq0 = (float)pb[(size_t)(t0-3)*kLdp + colb];
        bq1 = (float)pb[(size_t)(t0-2)*kLdp + colb];
        bq2 = (float)pb[(size_t)(t0-1)*kLdp + colb];
    }

    float hs[kN];
    #pragma unroll
    for (int n = 0; n < kN; ++n) hs[n] = 0.f;
    float Pp = 1.f;
    const float* dtp = dtv + (size_t)bh * kL;
    const float* dAp = dAv + (size_t)bh * kL;

    #pragma unroll 1
    for (int t = t0; t < t0 + kLC; ++t) {
        const size_t ro = (size_t)t * kLdp;
        float xv = (float)pb[ro + colx];
        float bv = (float)pb[ro + colb];
        float sx = silu_f(xbb + xw0*xq0 + xw1*xq1 + xw2*xq2 + xw3*xv);
        float sb = silu_f(bbb + bw0*bq0 + bw1*bq1 + bw2*bq2 + bw3*bv);
        xq0=xq1; xq1=xq2; xq2=xv;
        bq0=bq1; bq1=bq2; bq2=bv;
        float dt = dtp[t], dA = dAp[t];
        float dtx = dt * sx;
        Pp *= dA;
        #pragma unroll
        for (int n = 0; n < kN; ++n)
            hs[n] = fmaf(dA, hs[n], dtx * lane_bcast(sb, n));
    }
    float* cs = cstate + (size_t)blk * (kP * kN) + l * kN;
    #pragma unroll
    for (int n = 0; n < kN; ++n) cs[n] = hs[n];
    if (l == 0) Pch[blk] = Pp;
}

// ---------------- scan pass 2: sequential chunk combine (in place -> initial states) -----
__global__ __launch_bounds__(256) void scan_pass2_kernel(float* __restrict__ cstate,
                                                         const float* __restrict__ Pch) {
    const int bh  = blockIdx.x;
    const int off = threadIdx.x * 8;
    float s[8];
    #pragma unroll
    for (int i = 0; i < 8; ++i) s[i] = 0.f;
    float* base = cstate + (size_t)bh * (kNC * kP * kN) + off;
    #pragma unroll 1
    for (int c = 0; c < kNC; ++c) {
        float* cs = base + c * (kP * kN);
        float Pp = Pch[bh * kNC + c];
        #pragma unroll
        for (int i = 0; i < 8; ++i) {
            float loc = cs[i];
            cs[i] = s[i];                 // state entering chunk c
            s[i] = fmaf(Pp, s[i], loc);   // state entering chunk c+1
        }
    }
}

// ---------------- scan pass 3: replay chunk from known init state, emit y ----------------
__global__ __launch_bounds__(64) void scan_pass3_kernel(
    const _Float16* __restrict__ projh, const float* __restrict__ conv_w,
    const float* __restrict__ conv_b, const float* __restrict__ dtv,
    const float* __restrict__ dAv, const float* __restrict__ cstate,
    const float* __restrict__ D_param, float* __restrict__ ypre)
{
    const int blk = blockIdx.x;
    const int c   = blk & (kNC - 1);
    const int bh  = blk >> 4;
    const int h   = bh & (kH - 1);
    const int b   = bh >> 5;
    const int l   = threadIdx.x;
    const int t0  = c * kLC;

    const int chx = h * kP + l;      // x conv channel
    const int chc = 2048 + l;        // lanes 0..31 -> B channels, 32..63 -> C channels
    const float xw0 = conv_w[chx*4+0], xw1 = conv_w[chx*4+1], xw2 = conv_w[chx*4+2], xw3 = conv_w[chx*4+3];
    const float xbb = conv_b[chx];
    const float cw0 = conv_w[chc*4+0], cw1 = conv_w[chc*4+1], cw2 = conv_w[chc*4+2], cw3 = conv_w[chc*4+3];
    const float cbb = conv_b[chc];

    const _Float16* pb = projh + (size_t)b * kL * kLdp;
    const int colx = 2048 + chx;
    const int colc = 2048 + chc;     // = 4096 + l

    float xq0=0.f, xq1=0.f, xq2=0.f, cq0=0.f, cq1=0.f, cq2=0.f;
    if (c > 0) {
        xq0 = (float)pb[(size_t)(t0-3)*kLdp + colx];
        xq1 = (float)pb[(size_t)(t0-2)*kLdp + colx];
        xq2 = (float)pb[(size_t)(t0-1)*kLdp + colx];
        cq0 = (float)pb[(size_t)(t0-3)*kLdp + colc];
        cq1 = (float)pb[(size_t)(t0-2)*kLdp + colc];
        cq2 = (float)pb[(size_t)(t0-1)*kLdp + colc];
    }

    float hs[kN];
    const float* cs = cstate + (size_t)blk * (kP * kN) + l * kN;
    #pragma unroll
    for (int n = 0; n < kN; ++n) hs[n] = cs[n];
    const float Dh = D_param[h];
    const float* dtp = dtv + (size_t)bh * kL;
    const float* dAp = dAv + (size_t)bh * kL;
    float* yo = ypre + (size_t)b * kL * kD + h * kP + l;

    #pragma unroll 1
    for (int t = t0; t < t0 + kLC; ++t) {
        const size_t ro = (size_t)t * kLdp;
        float xv = (float)pb[ro + colx];
        float cv = (float)pb[ro + colc];
        float sx = silu_f(xbb + xw0*xq0 + xw1*xq1 + xw2*xq2 + xw3*xv);
        float sc = silu_f(cbb + cw0*cq0 + cw1*cq1 + cw2*cq2 + cw3*cv);
        xq0=xq1; xq1=xq2; xq2=xv;
        cq0=cq1; cq1=cq2; cq2=cv;
        float dt = dtp[t], dA = dAp[t];
        float dtx = dt * sx;
        float y0 = Dh * sx, y1 = 0.f;
        #pragma unroll
        for (int n = 0; n < kN; ++n) {
            float bn = lane_bcast(sc, n);
            float cn = lane_bcast(sc, n + 32);
            hs[n] = fmaf(dA, hs[n], dtx * bn);
            if (n & 1) y1 = fmaf(hs[n], cn, y1);
            else       y0 = fmaf(hs[n], cn, y0);
        }
        yo[(size_t)t * kD] = y0 + y1;
    }
}

// ---------------- gated RMSNorm -> f16 ----------------
__global__ __launch_bounds__(256) void gated_norm_kernel(
    const float* __restrict__ ypre, const _Float16* __restrict__ projh,
    const float* __restrict__ norm_w, _Float16* __restrict__ yh)
{
    const int row = blockIdx.x;
    const int tid = threadIdx.x;
    const float* yr = ypre + (size_t)row * kD;
    const _Float16* gr = projh + (size_t)row * kLdp;   // gate = cols [0,2048)
    float v[8];
    float ss = 0.f;
    #pragma unroll
    for (int u = 0; u < 8; ++u) {
        int col = tid + u * 256;
        float g = (float)gr[col];
        float t = yr[col] * (g / (1.f + __expf(-g)));
        v[u] = t;
        ss = fmaf(t, t, ss);
    }
    #pragma unroll
    for (int off = 32; off > 0; off >>= 1) ss += __shfl_xor(ss, off, 64);
    __shared__ float red[4];
    if ((tid & 63) == 0) red[tid >> 6] = ss;
    __syncthreads();
    float tot = (red[0] + red[1]) + (red[2] + red[3]);
    float scl = rsqrtf(tot * (1.f / (float)kD) + 1e-6f);
    #pragma unroll
    for (int u = 0; u < 8; ++u) {
        int col = tid + u * 256;
        yh[(size_t)row * kD + col] = (_Float16)(v[u] * scl * norm_w[col]);
    }
}

// ---------------- launcher ----------------
extern "C" void kernel_launch(void* const* d_in, const int* in_sizes, int n_in,
                              void* d_out, int out_size, void* d_ws, size_t ws_size,
                              hipStream_t stream)
{
    (void)in_sizes; (void)n_in; (void)out_size; (void)ws_size;
    const float* x       = (const float*)d_in[0];
    const float* W_in    = (const float*)d_in[1];
    const float* b_in    = (const float*)d_in[2];
    const float* conv_w  = (const float*)d_in[3];
    const float* conv_b  = (const float*)d_in[4];
    const float* A_log   = (const float*)d_in[5];
    const float* dt_bias = (const float*)d_in[6];
    const float* D_param = (const float*)d_in[7];
    const float* norm_w  = (const float*)d_in[8];
    const float* W_out   = (const float*)d_in[9];
    float* out = (float*)d_out;

    char* p = (char*)d_ws;
    _Float16* projh = (_Float16*)p; p += (size_t)kM * kLdp * 2;     // 69.2 MB
    _Float16* xh    = (_Float16*)p; p += (size_t)kM * kD * 2;       // 33.6 MB (reused as yh)
    _Float16* Wt    = (_Float16*)p; p += (size_t)kLdp * kK * 2;     // 17.3 MB
    _Float16* Wot   = (_Float16*)p; p += (size_t)kD * kK * 2;       //  8.4 MB
    float* dtraw    = (float*)p;    p += (size_t)kM * kH * 4;       //  1.0 MB
    float* dtv      = (float*)p;    p += (size_t)kB * kH * kL * 4;  //  1.0 MB
    float* dAv      = (float*)p;    p += (size_t)kB * kH * kL * 4;  //  1.0 MB
    float* cstate   = (float*)p;    p += (size_t)kB * kH * kNC * kP * kN * 4; // 16.8 MB
    float* Pch      = (float*)p;    p += (size_t)kB * kH * kNC * 4;
    _Float16* yh = xh;            // xh dead after GEMM1
    float* ypre = out;            // d_out used as fp32 scratch, overwritten by GEMM2

    // 1. cast x -> f16
    cast_f16_kernel<<<(kM * kD) / (256 * 8), 256, 0, stream>>>(x, xh);
    // 2-3. transpose+cast weights to N x K (pad W_in cols 4192->4224 with zeros)
    transpose_cast_kernel<<<dim3(kLdp / 32, kK / 32), 256, 0, stream>>>(W_in, Wt, kK, kProjW);
    transpose_cast_kernel<<<dim3(kD / 32, kK / 32), 256, 0, stream>>>(W_out, Wot, kK, kD);
    // 4. GEMM1: proj = x @ W_in + b_in  (f16 out + fp32 dt_raw sidecar)
    gemm_bt_kernel<true><<<dim3(kLdp / 128, kM / 128), 256, 0, stream>>>(
        xh, Wt, b_in, kProjW, (void*)projh, kK, kLdp, dtraw);
    // 5. dt / dA
    dt_da_kernel<<<(kB * kH * kL) / 256, 256, 0, stream>>>(dtraw, A_log, dt_bias, dtv, dAv);
    // 6-8. chunked scan (conv fused)
    scan_pass1_kernel<<<kB * kH * kNC, 64, 0, stream>>>(projh, conv_w, conv_b, dtv, dAv, cstate, Pch);
    scan_pass2_kernel<<<kB * kH, 256, 0, stream>>>(cstate, Pch);
    scan_pass3_kernel<<<kB * kH * kNC, 64, 0, stream>>>(projh, conv_w, conv_b, dtv, dAv, cstate, D_param, ypre);
    // 9. gated RMSNorm -> f16
    gated_norm_kernel<<<kM, 256, 0, stream>>>(ypre, projh, norm_w, yh);
    // 10. GEMM2: out = y @ W_out
    gemm_bt_kernel<false><<<dim3(kD / 128, kM / 128), 256, 0, stream>>>(
        yh, Wot, nullptr, 0, (void*)out, kK, kD, nullptr);
}

// Round 2
// 797.430 us; speedup vs baseline: 1.0927x; 1.0927x over previous
//
#include <hip/hip_runtime.h>
#include <cstdint>
#include <cstddef>

// ---- fixed problem shape ----
constexpr int kB    = 4;
constexpr int kL    = 2048;
constexpr int kH    = 32;
constexpr int kP    = 64;
constexpr int kN    = 32;
constexpr int kD    = 2048;      // d_model
constexpr int kProjW = 4192;
constexpr int kLdp  = 4224;      // padded proj width = 33*128
constexpr int kM    = kB * kL;   // 8192
constexpr int kK    = kD;        // 2048
constexpr int kLC   = 128;       // scan chunk length
constexpr int kNC   = kL / kLC;  // 16

typedef _Float16 f16x8 __attribute__((ext_vector_type(8)));
typedef float f32x4 __attribute__((ext_vector_type(4)));

__device__ __forceinline__ float lane_bcast(float v, int lane) {
    return __int_as_float(__builtin_amdgcn_readlane(__float_as_int(v), lane));
}
__device__ __forceinline__ float silu_f(float x) { return x / (1.f + __expf(-x)); }

__device__ __forceinline__ void async_copy16(const void* g, void* lds) {
    __builtin_amdgcn_global_load_lds(
        (const __attribute__((address_space(1))) unsigned int*)(uintptr_t)g,
        (__attribute__((address_space(3))) unsigned int*)(uintptr_t)lds,
        16, 0, 0);
}

// ---------------- cast fp32 -> fp16 (8 elems/thread) ----------------
__global__ __launch_bounds__(256) void cast_f16_kernel(const float* __restrict__ in,
                                                       _Float16* __restrict__ out) {
    size_t i = ((size_t)blockIdx.x * 256 + threadIdx.x) * 8;
    float4 a = *(const float4*)(in + i);
    float4 b = *(const float4*)(in + i + 4);
    f16x8 o;
    o[0] = (_Float16)a.x; o[1] = (_Float16)a.y; o[2] = (_Float16)a.z; o[3] = (_Float16)a.w;
    o[4] = (_Float16)b.x; o[5] = (_Float16)b.y; o[6] = (_Float16)b.z; o[7] = (_Float16)b.w;
    *(f16x8*)(out + i) = o;
}

// ------------- transpose + cast: W (R x C fp32) -> Wt (Cpad x R f16), zero pad -------------
__global__ __launch_bounds__(256) void transpose_cast_kernel(const float* __restrict__ W,
                                                             _Float16* __restrict__ Wt,
                                                             int R, int C) {
    __shared__ float tile[32][33];
    const int c0 = blockIdx.x * 32;
    const int r0 = blockIdx.y * 32;
    const int tx = threadIdx.x & 31;
    const int ty = threadIdx.x >> 5;   // 0..7
    #pragma unroll
    for (int i = 0; i < 32; i += 8) {
        int rr = r0 + ty + i;
        int cc = c0 + tx;
        tile[ty + i][tx] = (cc < C) ? W[(size_t)rr * C + cc] : 0.f;
    }
    __syncthreads();
    #pragma unroll
    for (int i = 0; i < 32; i += 8) {
        int cc = c0 + ty + i;          // row in Wt
        int rr = r0 + tx;              // col in Wt
        Wt[(size_t)cc * R + rr] = (_Float16)tile[tx][ty + i];
    }
}

// ---------------- GEMM: C[M x N] = A[M x K] * Bt[N x K]^T (+bias) ----------------
// 128x128 tile, BK=32, 256 threads (4 waves), 16x16x32 f16 MFMA.
// 3-stage software pipeline: 3 LDS buffers, raw s_barrier + explicit
// s_waitcnt vmcnt(4) so the NEXT tile's global_load_lds stay in flight across
// the barrier (never drain to vmcnt(0) except on the last iteration).
// Safety: slot (k+2)%3 was last ds_read in iter k-1; every wave's iter k-1
// reads retire (lgkm waits before MFMA issue) before it reaches iter k's
// barrier, so post-barrier DMA into that slot cannot race the reads.
// XCD swizzle: xcd=pid&7 owns m-band [xcd*8, xcd*8+8) (8 A-tiles = 4MB,
// L2-resident); within an XCD, 8 consecutive blocks share one B-tile.
template <bool OUT_F16>
__global__ __launch_bounds__(256, 3) void gemm_bt_kernel(
    const _Float16* __restrict__ A, const _Float16* __restrict__ Bt,
    const float* __restrict__ bias, int nbias,
    void* __restrict__ Cout, int K, int ldc, float* __restrict__ dtside)
{
    __shared__ __attribute__((aligned(16))) _Float16 As[3][128 * 32];
    __shared__ __attribute__((aligned(16))) _Float16 Bs[3][128 * 32];

    const int tid = threadIdx.x;
    const int w   = tid >> 6;
    const int l   = tid & 63;
    const int r   = l & 15;
    const int q   = l >> 4;
    const int wr = w >> 1, wc = w & 1;

    // XCD-aware swizzle (bijective for num_m == 64)
    const int pid = blockIdx.x;
    const int idx = pid >> 3;
    const int m_idx = (pid & 7) * 8 + (idx & 7);
    const int n_idx = idx >> 3;

    const size_t tileM = (size_t)m_idx * 128;
    const size_t tileN = (size_t)n_idx * 128;

    const _Float16* ga0 = A  + (tileM + (size_t)(w * 16 + r)) * K + q * 8;
    const _Float16* ga1 = A  + (tileM + (size_t)((w + 4) * 16 + r)) * K + q * 8;
    const _Float16* gb0 = Bt + (tileN + (size_t)(w * 16 + r)) * K + q * 8;
    const _Float16* gb1 = Bt + (tileN + (size_t)((w + 4) * 16 + r)) * K + q * 8;

    const int T = K >> 5;

    // prologue: stage tile 0 -> slot 0, tile 1 -> slot 1 (issue order matters)
    async_copy16(ga0, &As[0][w * 512]);
    async_copy16(ga1, &As[0][(w + 4) * 512]);
    async_copy16(gb0, &Bs[0][w * 512]);
    async_copy16(gb1, &Bs[0][(w + 4) * 512]);
    ga0 += 32; ga1 += 32; gb0 += 32; gb1 += 32;
    async_copy16(ga0, &As[1][w * 512]);
    async_copy16(ga1, &As[1][(w + 4) * 512]);
    async_copy16(gb0, &Bs[1][w * 512]);
    async_copy16(gb1, &Bs[1][(w + 4) * 512]);
    ga0 += 32; ga1 += 32; gb0 += 32; gb1 += 32;

    f32x4 acc[4][4] = {};
    int cs = 0;

    for (int k = 0; k < T; ++k) {
        // wait for tile k only (tile k+1's 4 loads stay in flight)
        if (k + 1 < T) asm volatile("s_waitcnt vmcnt(4)" ::: "memory");
        else           asm volatile("s_waitcnt vmcnt(0)" ::: "memory");
        asm volatile("s_barrier" ::: "memory");
        if (k + 2 < T) {
            int ns = cs + 2; if (ns >= 3) ns -= 3;
            async_copy16(ga0, &As[ns][w * 512]);
            async_copy16(ga1, &As[ns][(w + 4) * 512]);
            async_copy16(gb0, &Bs[ns][w * 512]);
            async_copy16(gb1, &Bs[ns][(w + 4) * 512]);
            ga0 += 32; ga1 += 32; gb0 += 32; gb1 += 32;
        }
        f16x8 af[4], bfr[4];
        #pragma unroll
        for (int i = 0; i < 4; ++i)
            af[i] = *(const f16x8*)&As[cs][(wr * 4 + i) * 512 + l * 8];
        #pragma unroll
        for (int j = 0; j < 4; ++j)
            bfr[j] = *(const f16x8*)&Bs[cs][(wc * 4 + j) * 512 + l * 8];
        #pragma unroll
        for (int i = 0; i < 4; ++i)
            #pragma unroll
            for (int j = 0; j < 4; ++j)
                acc[i][j] = __builtin_amdgcn_mfma_f32_16x16x32_f16(af[i], bfr[j], acc[i][j], 0, 0, 0);
        cs = (cs + 1 >= 3) ? 0 : cs + 1;
    }

    #pragma unroll
    for (int j = 0; j < 4; ++j) {
        const int col = (int)tileN + wc * 64 + j * 16 + r;
        float bv = 0.f;
        if (bias != nullptr && col < nbias) bv = bias[col];
        #pragma unroll
        for (int i = 0; i < 4; ++i) {
            const size_t row = tileM + (size_t)(wr * 64 + i * 16 + q * 4);
            #pragma unroll
            for (int u = 0; u < 4; ++u) {
                float v = acc[i][j][u] + bv;
                if (OUT_F16) ((_Float16*)Cout)[(row + u) * ldc + col] = (_Float16)v;
                else         ((float*)Cout)[(row + u) * ldc + col] = v;
                if (dtside != nullptr && col >= 4160 && col < 4192)
                    dtside[(row + u) * 32 + (col - 4160)] = v;
            }
        }
    }
}

// ---------------- dt / dA precompute ----------------
__global__ __launch_bounds__(256) void dt_da_kernel(
    const float* __restrict__ dtraw, const float* __restrict__ A_log,
    const float* __restrict__ dt_bias, float* __restrict__ dtv, float* __restrict__ dAv)
{
    int idx = blockIdx.x * 256 + threadIdx.x;  // (b,h,t) t-minor
    int t  = idx & (kL - 1);
    int bh = idx >> 11;
    int h  = bh & (kH - 1);
    int b  = bh >> 5;
    float z  = dtraw[((size_t)(b * kL + t)) * kH + h] + dt_bias[h];
    float dt = (z > 20.f) ? z : log1pf(expf(z));
    float dA = expf(dt * -expf(A_log[h]));
    dtv[idx] = dt;
    dAv[idx] = dA;
}

// ---------------- scan pass 1: per-chunk local states (zero init) + decay product --------
__global__ __launch_bounds__(64) void scan_pass1_kernel(
    const _Float16* __restrict__ projh, const float* __restrict__ conv_w,
    const float* __restrict__ conv_b, const float* __restrict__ dtv,
    const float* __restrict__ dAv, float* __restrict__ cstate, float* __restrict__ Pch)
{
    const int blk = blockIdx.x;
    const int c   = blk & (kNC - 1);
    const int bh  = blk >> 4;
    const int h   = bh & (kH - 1);
    const int b   = bh >> 5;
    const int l   = threadIdx.x;
    const int t0  = c * kLC;

    const int chx = h * kP + l;          // x conv channel
    const int chb = 2048 + (l & 31);     // B conv channel (duplicated over half-wave)
    const float xw0 = conv_w[chx*4+0], xw1 = conv_w[chx*4+1], xw2 = conv_w[chx*4+2], xw3 = conv_w[chx*4+3];
    const float xbb = conv_b[chx];
    const float bw0 = conv_w[chb*4+0], bw1 = conv_w[chb*4+1], bw2 = conv_w[chb*4+2], bw3 = conv_w[chb*4+3];
    const float bbb = conv_b[chb];

    const _Float16* pb = projh + (size_t)b * kL * kLdp;
    const int colx = 2048 + chx;
    const int colb = 2048 + chb;

    float xq0=0.f, xq1=0.f, xq2=0.f, bq0=0.f, bq1=0.f, bq2=0.f;
    if (c > 0) {
        xq0 = (float)pb[(size_t)(t0-3)*kLdp + colx];
        xq1 = (float)pb[(size_t)(t0-2)*kLdp + colx];
        xq2 = (float)pb[(size_t)(t0-1)*kLdp + colx];
        bq0 = (float)pb[(size_t)(t0-3)*kLdp + colb];
        bq1 = (float)pb[(size_t)(t0-2)*kLdp + colb];
        bq2 = (float)pb[(size_t)(t0-1)*kLdp + colb];
    }

    float hs[kN];
    #pragma unroll
    for (int n = 0; n < kN; ++n) hs[n] = 0.f;
    float Pp = 1.f;
    const float* dtp = dtv + (size_t)bh * kL;
    const float* dAp = dAv + (size_t)bh * kL;

    #pragma unroll 1
    for (int t = t0; t < t0 + kLC; ++t) {
        const size_t ro = (size_t)t * kLdp;
        float xv = (float)pb[ro + colx];
        float bv = (float)pb[ro + colb];
        float sx = silu_f(xbb + xw0*xq0 + xw1*xq1 + xw2*xq2 + xw3*xv);
        float sb = silu_f(bbb + bw0*bq0 + bw1*bq1 + bw2*bq2 + bw3*bv);
        xq0=xq1; xq1=xq2; xq2=xv;
        bq0=bq1; bq1=bq2; bq2=bv;
        float dt = dtp[t], dA = dAp[t];
        float dtx = dt * sx;
        Pp *= dA;
        #pragma unroll
        for (int n = 0; n < kN; ++n)
            hs[n] = fmaf(dA, hs[n], dtx * lane_bcast(sb, n));
    }
    float* cs = cstate + (size_t)blk * (kP * kN) + l * kN;
    #pragma unroll
    for (int n = 0; n < kN; ++n) cs[n] = hs[n];
    if (l == 0) Pch[blk] = Pp;
}

// ---------------- scan pass 2: sequential chunk combine (in place -> initial states) -----
__global__ __launch_bounds__(256) void scan_pass2_kernel(float* __restrict__ cstate,
                                                         const float* __restrict__ Pch) {
    const int bh  = blockIdx.x;
    const int off = threadIdx.x * 8;
    float s[8];
    #pragma unroll
    for (int i = 0; i < 8; ++i) s[i] = 0.f;
    float* base = cstate + (size_t)bh * (kNC * kP * kN) + off;
    #pragma unroll 1
    for (int c = 0; c < kNC; ++c) {
        float* cs = base + c * (kP * kN);
        float Pp = Pch[bh * kNC + c];
        #pragma unroll
        for (int i = 0; i < 8; ++i) {
            float loc = cs[i];
            cs[i] = s[i];                 // state entering chunk c
            s[i] = fmaf(Pp, s[i], loc);   // state entering chunk c+1
        }
    }
}

// ---------------- scan pass 3: replay chunk from known init state, emit y ----------------
__global__ __launch_bounds__(64) void scan_pass3_kernel(
    const _Float16* __restrict__ projh, const float* __restrict__ conv_w,
    const float* __restrict__ conv_b, const float* __restrict__ dtv,
    const float* __restrict__ dAv, const float* __restrict__ cstate,
    const float* __restrict__ D_param, float* __restrict__ ypre)
{
    const int blk = blockIdx.x;
    const int c   = blk & (kNC - 1);
    const int bh  = blk >> 4;
    const int h   = bh & (kH - 1);
    const int b   = bh >> 5;
    const int l   = threadIdx.x;
    const int t0  = c * kLC;

    const int chx = h * kP + l;      // x conv channel
    const int chc = 2048 + l;        // lanes 0..31 -> B channels, 32..63 -> C channels
    const float xw0 = conv_w[chx*4+0], xw1 = conv_w[chx*4+1], xw2 = conv_w[chx*4+2], xw3 = conv_w[chx*4+3];
    const float xbb = conv_b[chx];
    const float cw0 = conv_w[chc*4+0], cw1 = conv_w[chc*4+1], cw2 = conv_w[chc*4+2], cw3 = conv_w[chc*4+3];
    const float cbb = conv_b[chc];

    const _Float16* pb = projh + (size_t)b * kL * kLdp;
    const int colx = 2048 + chx;
    const int colc = 2048 + chc;     // = 4096 + l

    float xq0=0.f, xq1=0.f, xq2=0.f, cq0=0.f, cq1=0.f, cq2=0.f;
    if (c > 0) {
        xq0 = (float)pb[(size_t)(t0-3)*kLdp + colx];
        xq1 = (float)pb[(size_t)(t0-2)*kLdp + colx];
        xq2 = (float)pb[(size_t)(t0-1)*kLdp + colx];
        cq0 = (float)pb[(size_t)(t0-3)*kLdp + colc];
        cq1 = (float)pb[(size_t)(t0-2)*kLdp + colc];
        cq2 = (float)pb[(size_t)(t0-1)*kLdp + colc];
    }

    float hs[kN];
    const float* cs = cstate + (size_t)blk * (kP * kN) + l * kN;
    #pragma unroll
    for (int n = 0; n < kN; ++n) hs[n] = cs[n];
    const float Dh = D_param[h];
    const float* dtp = dtv + (size_t)bh * kL;
    const float* dAp = dAv + (size_t)bh * kL;
    float* yo = ypre + (size_t)b * kL * kD + h * kP + l;

    #pragma unroll 1
    for (int t = t0; t < t0 + kLC; ++t) {
        const size_t ro = (size_t)t * kLdp;
        float xv = (float)pb[ro + colx];
        float cv = (float)pb[ro + colc];
        float sx = silu_f(xbb + xw0*xq0 + xw1*xq1 + xw2*xq2 + xw3*xv);
        float sc = silu_f(cbb + cw0*cq0 + cw1*cq1 + cw2*cq2 + cw3*cv);
        xq0=xq1; xq1=xq2; xq2=xv;
        cq0=cq1; cq1=cq2; cq2=cv;
        float dt = dtp[t], dA = dAp[t];
        float dtx = dt * sx;
        float y0 = Dh * sx, y1 = 0.f;
        #pragma unroll
        for (int n = 0; n < kN; ++n) {
            float bn = lane_bcast(sc, n);
            float cn = lane_bcast(sc, n + 32);
            hs[n] = fmaf(dA, hs[n], dtx * bn);
            if (n & 1) y1 = fmaf(hs[n], cn, y1);
            else       y0 = fmaf(hs[n], cn, y0);
        }
        yo[(size_t)t * kD] = y0 + y1;
    }
}

// ---------------- gated RMSNorm -> f16 ----------------
__global__ __launch_bounds__(256) void gated_norm_kernel(
    const float* __restrict__ ypre, const _Float16* __restrict__ projh,
    const float* __restrict__ norm_w, _Float16* __restrict__ yh)
{
    const int row = blockIdx.x;
    const int tid = threadIdx.x;
    const float* yr = ypre + (size_t)row * kD;
    const _Float16* gr = projh + (size_t)row * kLdp;   // gate = cols [0,2048)
    float v[8];
    float ss = 0.f;
    #pragma unroll
    for (int u = 0; u < 8; ++u) {
        int col = tid + u * 256;
        float g = (float)gr[col];
        float t = yr[col] * (g / (1.f + __expf(-g)));
        v[u] = t;
        ss = fmaf(t, t, ss);
    }
    #pragma unroll
    for (int off = 32; off > 0; off >>= 1) ss += __shfl_xor(ss, off, 64);
    __shared__ float red[4];
    if ((tid & 63) == 0) red[tid >> 6] = ss;
    __syncthreads();
    float tot = (red[0] + red[1]) + (red[2] + red[3]);
    float scl = rsqrtf(tot * (1.f / (float)kD) + 1e-6f);
    #pragma unroll
    for (int u = 0; u < 8; ++u) {
        int col = tid + u * 256;
        yh[(size_t)row * kD + col] = (_Float16)(v[u] * scl * norm_w[col]);
    }
}

// ---------------- launcher ----------------
extern "C" void kernel_launch(void* const* d_in, const int* in_sizes, int n_in,
                              void* d_out, int out_size, void* d_ws, size_t ws_size,
                              hipStream_t stream)
{
    (void)in_sizes; (void)n_in; (void)out_size; (void)ws_size;
    const float* x       = (const float*)d_in[0];
    const float* W_in    = (const float*)d_in[1];
    const float* b_in    = (const float*)d_in[2];
    const float* conv_w  = (const float*)d_in[3];
    const float* conv_b  = (const float*)d_in[4];
    const float* A_log   = (const float*)d_in[5];
    const float* dt_bias = (const float*)d_in[6];
    const float* D_param = (const float*)d_in[7];
    const float* norm_w  = (const float*)d_in[8];
    const float* W_out   = (const float*)d_in[9];
    float* out = (float*)d_out;

    char* p = (char*)d_ws;
    _Float16* projh = (_Float16*)p; p += (size_t)kM * kLdp * 2;     // 69.2 MB
    _Float16* xh    = (_Float16*)p; p += (size_t)kM * kD * 2;       // 33.6 MB (reused as yh)
    _Float16* Wt    = (_Float16*)p; p += (size_t)kLdp * kK * 2;     // 17.3 MB
    _Float16* Wot   = (_Float16*)p; p += (size_t)kD * kK * 2;       //  8.4 MB
    float* dtraw    = (float*)p;    p += (size_t)kM * kH * 4;       //  1.0 MB
    float* dtv      = (float*)p;    p += (size_t)kB * kH * kL * 4;  //  1.0 MB
    float* dAv      = (float*)p;    p += (size_t)kB * kH * kL * 4;  //  1.0 MB
    float* cstate   = (float*)p;    p += (size_t)kB * kH * kNC * kP * kN * 4; // 16.8 MB
    float* Pch      = (float*)p;    p += (size_t)kB * kH * kNC * 4;
    _Float16* yh = xh;            // xh dead after GEMM1
    float* ypre = out;            // d_out used as fp32 scratch, overwritten by GEMM2

    // 1. cast x -> f16
    cast_f16_kernel<<<(kM * kD) / (256 * 8), 256, 0, stream>>>(x, xh);
    // 2-3. transpose+cast weights to N x K (pad W_in cols 4192->4224 with zeros)
    transpose_cast_kernel<<<dim3(kLdp / 32, kK / 32), 256, 0, stream>>>(W_in, Wt, kK, kProjW);
    transpose_cast_kernel<<<dim3(kD / 32, kK / 32), 256, 0, stream>>>(W_out, Wot, kK, kD);
    // 4. GEMM1: proj = x @ W_in + b_in  (f16 out + fp32 dt_raw sidecar), 1D swizzled grid
    gemm_bt_kernel<true><<<(kLdp / 128) * (kM / 128), 256, 0, stream>>>(
        xh, Wt, b_in, kProjW, (void*)projh, kK, kLdp, dtraw);
    // 5. dt / dA
    dt_da_kernel<<<(kB * kH * kL) / 256, 256, 0, stream>>>(dtraw, A_log, dt_bias, dtv, dAv);
    // 6-8. chunked scan (conv fused)
    scan_pass1_kernel<<<kB * kH * kNC, 64, 0, stream>>>(projh, conv_w, conv_b, dtv, dAv, cstate, Pch);
    scan_pass2_kernel<<<kB * kH, 256, 0, stream>>>(cstate, Pch);
    scan_pass3_kernel<<<kB * kH * kNC, 64, 0, stream>>>(projh, conv_w, conv_b, dtv, dAv, cstate, D_param, ypre);
    // 9. gated RMSNorm -> f16
    gated_norm_kernel<<<kM, 256, 0, stream>>>(ypre, projh, norm_w, yh);
    // 10. GEMM2: out = y @ W_out
    gemm_bt_kernel<false><<<(kD / 128) * (kM / 128), 256, 0, stream>>>(
        yh, Wot, nullptr, 0, (void*)out, kK, kD, nullptr);
}

// Round 3
// 734.207 us; speedup vs baseline: 1.1868x; 1.0861x over previous
//
#include <hip/hip_runtime.h>
#include <cstdint>
#include <cstddef>

// ---- fixed problem shape ----
constexpr int kB    = 4;
constexpr int kL    = 2048;
constexpr int kH    = 32;
constexpr int kP    = 64;
constexpr int kN    = 32;
constexpr int kD    = 2048;      // d_model
constexpr int kProjW = 4192;
constexpr int kLdp  = 4224;      // padded proj width = 33*128
constexpr int kM    = kB * kL;   // 8192
constexpr int kK    = kD;        // 2048
constexpr int kLC   = 128;       // scan chunk length
constexpr int kNC   = kL / kLC;  // 16

typedef _Float16 f16x8 __attribute__((ext_vector_type(8)));
typedef float f32x4 __attribute__((ext_vector_type(4)));

__device__ __forceinline__ float lane_bcast(float v, int lane) {
    return __int_as_float(__builtin_amdgcn_readlane(__float_as_int(v), lane));
}
__device__ __forceinline__ float silu_f(float x) { return x / (1.f + __expf(-x)); }

__device__ __forceinline__ void async_copy16(const void* g, void* lds) {
    __builtin_amdgcn_global_load_lds(
        (const __attribute__((address_space(1))) unsigned int*)(uintptr_t)g,
        (__attribute__((address_space(3))) unsigned int*)(uintptr_t)lds,
        16, 0, 0);
}

// ---------------- cast fp32 -> fp16 (8 elems/thread) ----------------
__global__ __launch_bounds__(256) void cast_f16_kernel(const float* __restrict__ in,
                                                       _Float16* __restrict__ out) {
    size_t i = ((size_t)blockIdx.x * 256 + threadIdx.x) * 8;
    float4 a = *(const float4*)(in + i);
    float4 b = *(const float4*)(in + i + 4);
    f16x8 o;
    o[0] = (_Float16)a.x; o[1] = (_Float16)a.y; o[2] = (_Float16)a.z; o[3] = (_Float16)a.w;
    o[4] = (_Float16)b.x; o[5] = (_Float16)b.y; o[6] = (_Float16)b.z; o[7] = (_Float16)b.w;
    *(f16x8*)(out + i) = o;
}

// ------------- transpose + cast: W (R x C fp32) -> Wt (Cpad x R f16), zero pad -------------
__global__ __launch_bounds__(256) void transpose_cast_kernel(const float* __restrict__ W,
                                                             _Float16* __restrict__ Wt,
                                                             int R, int C) {
    __shared__ float tile[32][33];
    const int c0 = blockIdx.x * 32;
    const int r0 = blockIdx.y * 32;
    const int tx = threadIdx.x & 31;
    const int ty = threadIdx.x >> 5;   // 0..7
    #pragma unroll
    for (int i = 0; i < 32; i += 8) {
        int rr = r0 + ty + i;
        int cc = c0 + tx;
        tile[ty + i][tx] = (cc < C) ? W[(size_t)rr * C + cc] : 0.f;
    }
    __syncthreads();
    #pragma unroll
    for (int i = 0; i < 32; i += 8) {
        int cc = c0 + ty + i;          // row in Wt
        int rr = r0 + tx;              // col in Wt
        Wt[(size_t)cc * R + rr] = (_Float16)tile[tx][ty + i];
    }
}

// ---------------- GEMM: C[M x N] = A[M x K] * Bt[N x K]^T (+bias) ----------------
// 256x128 tile, BK=32, 256 threads (4 waves), 16x16x32 f16 MFMA.
// Arithmetic intensity: 24 KB staged per 2.1 MFLOP (87 FLOP/B) -> L2 demand
// ~27 TB/s at full MFMA rate (under the 34.5 TB/s ceiling); one iter is
// ~1240 cyc/CU so the 2-tile-ahead prefetch covers ~2500 cyc > HBM latency.
// 3-stage pipeline: raw s_barrier + s_waitcnt vmcnt(6) (next tile's 6 loads
// per thread stay in flight across the barrier; vmcnt(0) only on last iter).
// Safety: slot (k+2)%3 was last ds_read in iter k-1; register deps force all
// of a wave's iter-(k-1) ds_reads to retire before it issues its last MFMA,
// which precedes iter k's barrier, so post-barrier DMA can't race the reads.
// Per-wave layout: wave w owns rows [64w,64w+64) x all 128 cols:
// acc[4][8] (128 AGPR), af from A-groups 4w+i, bf from all 8 B-groups.
// XCD swizzle: xcd=pid&7 owns m-band of 4 m-tiles; n advances every 4 blocks.
template <bool OUT_F16>
__global__ __launch_bounds__(256, 2) void gemm_bt_kernel(
    const _Float16* __restrict__ A, const _Float16* __restrict__ Bt,
    const float* __restrict__ bias, int nbias,
    void* __restrict__ Cout, int K, int ldc, float* __restrict__ dtside)
{
    __shared__ __attribute__((aligned(16))) _Float16 As[3][256 * 32]; // 16 KB/stage
    __shared__ __attribute__((aligned(16))) _Float16 Bs[3][128 * 32]; //  8 KB/stage

    const int tid = threadIdx.x;
    const int w   = tid >> 6;
    const int l   = tid & 63;
    const int r   = l & 15;
    const int q   = l >> 4;

    // XCD-aware swizzle (M = 8192 -> 32 m-tiles = 8 XCDs x 4)
    const int pid = blockIdx.x;
    const int i0  = pid >> 3;
    const int m_idx = (pid & 7) * 4 + (i0 & 3);
    const int n_idx = i0 >> 2;

    const size_t tileM = (size_t)m_idx * 256;
    const size_t tileN = (size_t)n_idx * 128;

    // per-lane staging addresses: A groups {w, w+4, w+8, w+12}, B groups {w, w+4}
    const _Float16* gA[4];
    #pragma unroll
    for (int g = 0; g < 4; ++g)
        gA[g] = A + (tileM + (size_t)((w + g * 4) * 16 + r)) * K + q * 8;
    const _Float16* gB[2];
    #pragma unroll
    for (int g = 0; g < 2; ++g)
        gB[g] = Bt + (tileN + (size_t)((w + g * 4) * 16 + r)) * K + q * 8;

    auto stage = [&](int s, int koff) {
        #pragma unroll
        for (int g = 0; g < 4; ++g)
            async_copy16(gA[g] + koff, &As[s][(w + g * 4) * 512]);
        #pragma unroll
        for (int g = 0; g < 2; ++g)
            async_copy16(gB[g] + koff, &Bs[s][(w + g * 4) * 512]);
    };

    const int T = K >> 5;
    stage(0, 0);
    stage(1, 32);

    f32x4 acc[4][8] = {};
    int cs = 0;

    for (int k = 0; k < T; ++k) {
        if (k + 1 < T) asm volatile("s_waitcnt vmcnt(6)" ::: "memory");
        else           asm volatile("s_waitcnt vmcnt(0)" ::: "memory");
        asm volatile("s_barrier" ::: "memory");
        if (k + 2 < T) {
            int ns = cs + 2; if (ns >= 3) ns -= 3;
            stage(ns, (k + 2) * 32);
        }
        f16x8 af[4], bf[8];
        #pragma unroll
        for (int i = 0; i < 4; ++i)
            af[i] = *(const f16x8*)&As[cs][(w * 4 + i) * 512 + l * 8];
        #pragma unroll
        for (int j = 0; j < 8; ++j)
            bf[j] = *(const f16x8*)&Bs[cs][j * 512 + l * 8];
        #pragma unroll
        for (int i = 0; i < 4; ++i)
            #pragma unroll
            for (int j = 0; j < 8; ++j)
                acc[i][j] = __builtin_amdgcn_mfma_f32_16x16x32_f16(af[i], bf[j], acc[i][j], 0, 0, 0);
        cs = (cs + 1 >= 3) ? 0 : cs + 1;
    }

    #pragma unroll
    for (int j = 0; j < 8; ++j) {
        const int col = (int)tileN + j * 16 + r;
        float bv = 0.f;
        if (bias != nullptr && col < nbias) bv = bias[col];
        #pragma unroll
        for (int i = 0; i < 4; ++i) {
            const size_t row = tileM + (size_t)(w * 64 + i * 16 + q * 4);
            #pragma unroll
            for (int u = 0; u < 4; ++u) {
                float v = acc[i][j][u] + bv;
                if (OUT_F16) ((_Float16*)Cout)[(row + u) * ldc + col] = (_Float16)v;
                else         ((float*)Cout)[(row + u) * ldc + col] = v;
                if (dtside != nullptr && col >= 4160 && col < 4192)
                    dtside[(row + u) * 32 + (col - 4160)] = v;
            }
        }
    }
}

// ---------------- dt / dA precompute ----------------
__global__ __launch_bounds__(256) void dt_da_kernel(
    const float* __restrict__ dtraw, const float* __restrict__ A_log,
    const float* __restrict__ dt_bias, float* __restrict__ dtv, float* __restrict__ dAv)
{
    int idx = blockIdx.x * 256 + threadIdx.x;  // (b,h,t) t-minor
    int t  = idx & (kL - 1);
    int bh = idx >> 11;
    int h  = bh & (kH - 1);
    int b  = bh >> 5;
    float z  = dtraw[((size_t)(b * kL + t)) * kH + h] + dt_bias[h];
    float dt = (z > 20.f) ? z : log1pf(expf(z));
    float dA = expf(dt * -expf(A_log[h]));
    dtv[idx] = dt;
    dAv[idx] = dA;
}

// ---------------- scan pass 1: per-chunk local states (zero init) + decay product --------
__global__ __launch_bounds__(64) void scan_pass1_kernel(
    const _Float16* __restrict__ projh, const float* __restrict__ conv_w,
    const float* __restrict__ conv_b, const float* __restrict__ dtv,
    const float* __restrict__ dAv, float* __restrict__ cstate, float* __restrict__ Pch)
{
    const int blk = blockIdx.x;
    const int c   = blk & (kNC - 1);
    const int bh  = blk >> 4;
    const int h   = bh & (kH - 1);
    const int b   = bh >> 5;
    const int l   = threadIdx.x;
    const int t0  = c * kLC;

    const int chx = h * kP + l;          // x conv channel
    const int chb = 2048 + (l & 31);     // B conv channel (duplicated over half-wave)
    const float xw0 = conv_w[chx*4+0], xw1 = conv_w[chx*4+1], xw2 = conv_w[chx*4+2], xw3 = conv_w[chx*4+3];
    const float xbb = conv_b[chx];
    const float bw0 = conv_w[chb*4+0], bw1 = conv_w[chb*4+1], bw2 = conv_w[chb*4+2], bw3 = conv_w[chb*4+3];
    const float bbb = conv_b[chb];

    const _Float16* pb = projh + (size_t)b * kL * kLdp;
    const int colx = 2048 + chx;
    const int colb = 2048 + chb;

    float xq0=0.f, xq1=0.f, xq2=0.f, bq0=0.f, bq1=0.f, bq2=0.f;
    if (c > 0) {
        xq0 = (float)pb[(size_t)(t0-3)*kLdp + colx];
        xq1 = (float)pb[(size_t)(t0-2)*kLdp + colx];
        xq2 = (float)pb[(size_t)(t0-1)*kLdp + colx];
        bq0 = (float)pb[(size_t)(t0-3)*kLdp + colb];
        bq1 = (float)pb[(size_t)(t0-2)*kLdp + colb];
        bq2 = (float)pb[(size_t)(t0-1)*kLdp + colb];
    }

    float hs[kN];
    #pragma unroll
    for (int n = 0; n < kN; ++n) hs[n] = 0.f;
    float Pp = 1.f;
    const float* dtp = dtv + (size_t)bh * kL;
    const float* dAp = dAv + (size_t)bh * kL;

    #pragma unroll 1
    for (int t = t0; t < t0 + kLC; ++t) {
        const size_t ro = (size_t)t * kLdp;
        float xv = (float)pb[ro + colx];
        float bv = (float)pb[ro + colb];
        float sx = silu_f(xbb + xw0*xq0 + xw1*xq1 + xw2*xq2 + xw3*xv);
        float sb = silu_f(bbb + bw0*bq0 + bw1*bq1 + bw2*bq2 + bw3*bv);
        xq0=xq1; xq1=xq2; xq2=xv;
        bq0=bq1; bq1=bq2; bq2=bv;
        float dt = dtp[t], dA = dAp[t];
        float dtx = dt * sx;
        Pp *= dA;
        #pragma unroll
        for (int n = 0; n < kN; ++n)
            hs[n] = fmaf(dA, hs[n], dtx * lane_bcast(sb, n));
    }
    float* cs = cstate + (size_t)blk * (kP * kN) + l * kN;
    #pragma unroll
    for (int n = 0; n < kN; ++n) cs[n] = hs[n];
    if (l == 0) Pch[blk] = Pp;
}

// ---------------- scan pass 2: sequential chunk combine (in place -> initial states) -----
__global__ __launch_bounds__(256) void scan_pass2_kernel(float* __restrict__ cstate,
                                                         const float* __restrict__ Pch) {
    const int bh  = blockIdx.x;
    const int off = threadIdx.x * 8;
    float s[8];
    #pragma unroll
    for (int i = 0; i < 8; ++i) s[i] = 0.f;
    float* base = cstate + (size_t)bh * (kNC * kP * kN) + off;
    #pragma unroll 1
    for (int c = 0; c < kNC; ++c) {
        float* cs = base + c * (kP * kN);
        float Pp = Pch[bh * kNC + c];
        #pragma unroll
        for (int i = 0; i < 8; ++i) {
            float loc = cs[i];
            cs[i] = s[i];                 // state entering chunk c
            s[i] = fmaf(Pp, s[i], loc);   // state entering chunk c+1
        }
    }
}

// ---------------- scan pass 3: replay chunk from known init state, emit y ----------------
__global__ __launch_bounds__(64) void scan_pass3_kernel(
    const _Float16* __restrict__ projh, const float* __restrict__ conv_w,
    const float* __restrict__ conv_b, const float* __restrict__ dtv,
    const float* __restrict__ dAv, const float* __restrict__ cstate,
    const float* __restrict__ D_param, float* __restrict__ ypre)
{
    const int blk = blockIdx.x;
    const int c   = blk & (kNC - 1);
    const int bh  = blk >> 4;
    const int h   = bh & (kH - 1);
    const int b   = bh >> 5;
    const int l   = threadIdx.x;
    const int t0  = c * kLC;

    const int chx = h * kP + l;      // x conv channel
    const int chc = 2048 + l;        // lanes 0..31 -> B channels, 32..63 -> C channels
    const float xw0 = conv_w[chx*4+0], xw1 = conv_w[chx*4+1], xw2 = conv_w[chx*4+2], xw3 = conv_w[chx*4+3];
    const float xbb = conv_b[chx];
    const float cw0 = conv_w[chc*4+0], cw1 = conv_w[chc*4+1], cw2 = conv_w[chc*4+2], cw3 = conv_w[chc*4+3];
    const float cbb = conv_b[chc];

    const _Float16* pb = projh + (size_t)b * kL * kLdp;
    const int colx = 2048 + chx;
    const int colc = 2048 + chc;     // = 4096 + l

    float xq0=0.f, xq1=0.f, xq2=0.f, cq0=0.f, cq1=0.f, cq2=0.f;
    if (c > 0) {
        xq0 = (float)pb[(size_t)(t0-3)*kLdp + colx];
        xq1 = (float)pb[(size_t)(t0-2)*kLdp + colx];
        xq2 = (float)pb[(size_t)(t0-1)*kLdp + colx];
        cq0 = (float)pb[(size_t)(t0-3)*kLdp + colc];
        cq1 = (float)pb[(size_t)(t0-2)*kLdp + colc];
        cq2 = (float)pb[(size_t)(t0-1)*kLdp + colc];
    }

    float hs[kN];
    const float* cs = cstate + (size_t)blk * (kP * kN) + l * kN;
    #pragma unroll
    for (int n = 0; n < kN; ++n) hs[n] = cs[n];
    const float Dh = D_param[h];
    const float* dtp = dtv + (size_t)bh * kL;
    const float* dAp = dAv + (size_t)bh * kL;
    float* yo = ypre + (size_t)b * kL * kD + h * kP + l;

    #pragma unroll 1
    for (int t = t0; t < t0 + kLC; ++t) {
        const size_t ro = (size_t)t * kLdp;
        float xv = (float)pb[ro + colx];
        float cv = (float)pb[ro + colc];
        float sx = silu_f(xbb + xw0*xq0 + xw1*xq1 + xw2*xq2 + xw3*xv);
        float sc = silu_f(cbb + cw0*cq0 + cw1*cq1 + cw2*cq2 + cw3*cv);
        xq0=xq1; xq1=xq2; xq2=xv;
        cq0=cq1; cq1=cq2; cq2=cv;
        float dt = dtp[t], dA = dAp[t];
        float dtx = dt * sx;
        float y0 = Dh * sx, y1 = 0.f;
        #pragma unroll
        for (int n = 0; n < kN; ++n) {
            float bn = lane_bcast(sc, n);
            float cn = lane_bcast(sc, n + 32);
            hs[n] = fmaf(dA, hs[n], dtx * bn);
            if (n & 1) y1 = fmaf(hs[n], cn, y1);
            else       y0 = fmaf(hs[n], cn, y0);
        }
        yo[(size_t)t * kD] = y0 + y1;
    }
}

// ---------------- gated RMSNorm -> f16 ----------------
__global__ __launch_bounds__(256) void gated_norm_kernel(
    const float* __restrict__ ypre, const _Float16* __restrict__ projh,
    const float* __restrict__ norm_w, _Float16* __restrict__ yh)
{
    const int row = blockIdx.x;
    const int tid = threadIdx.x;
    const float* yr = ypre + (size_t)row * kD;
    const _Float16* gr = projh + (size_t)row * kLdp;   // gate = cols [0,2048)
    float v[8];
    float ss = 0.f;
    #pragma unroll
    for (int u = 0; u < 8; ++u) {
        int col = tid + u * 256;
        float g = (float)gr[col];
        float t = yr[col] * (g / (1.f + __expf(-g)));
        v[u] = t;
        ss = fmaf(t, t, ss);
    }
    #pragma unroll
    for (int off = 32; off > 0; off >>= 1) ss += __shfl_xor(ss, off, 64);
    __shared__ float red[4];
    if ((tid & 63) == 0) red[tid >> 6] = ss;
    __syncthreads();
    float tot = (red[0] + red[1]) + (red[2] + red[3]);
    float scl = rsqrtf(tot * (1.f / (float)kD) + 1e-6f);
    #pragma unroll
    for (int u = 0; u < 8; ++u) {
        int col = tid + u * 256;
        yh[(size_t)row * kD + col] = (_Float16)(v[u] * scl * norm_w[col]);
    }
}

// ---------------- launcher ----------------
extern "C" void kernel_launch(void* const* d_in, const int* in_sizes, int n_in,
                              void* d_out, int out_size, void* d_ws, size_t ws_size,
                              hipStream_t stream)
{
    (void)in_sizes; (void)n_in; (void)out_size; (void)ws_size;
    const float* x       = (const float*)d_in[0];
    const float* W_in    = (const float*)d_in[1];
    const float* b_in    = (const float*)d_in[2];
    const float* conv_w  = (const float*)d_in[3];
    const float* conv_b  = (const float*)d_in[4];
    const float* A_log   = (const float*)d_in[5];
    const float* dt_bias = (const float*)d_in[6];
    const float* D_param = (const float*)d_in[7];
    const float* norm_w  = (const float*)d_in[8];
    const float* W_out   = (const float*)d_in[9];
    float* out = (float*)d_out;

    char* p = (char*)d_ws;
    _Float16* projh = (_Float16*)p; p += (size_t)kM * kLdp * 2;     // 69.2 MB
    _Float16* xh    = (_Float16*)p; p += (size_t)kM * kD * 2;       // 33.6 MB (reused as yh)
    _Float16* Wt    = (_Float16*)p; p += (size_t)kLdp * kK * 2;     // 17.3 MB
    _Float16* Wot   = (_Float16*)p; p += (size_t)kD * kK * 2;       //  8.4 MB
    float* dtraw    = (float*)p;    p += (size_t)kM * kH * 4;       //  1.0 MB
    float* dtv      = (float*)p;    p += (size_t)kB * kH * kL * 4;  //  1.0 MB
    float* dAv      = (float*)p;    p += (size_t)kB * kH * kL * 4;  //  1.0 MB
    float* cstate   = (float*)p;    p += (size_t)kB * kH * kNC * kP * kN * 4; // 16.8 MB
    float* Pch      = (float*)p;    p += (size_t)kB * kH * kNC * 4;
    _Float16* yh = xh;            // xh dead after GEMM1
    float* ypre = out;            // d_out used as fp32 scratch, overwritten by GEMM2

    // 1. cast x -> f16
    cast_f16_kernel<<<(kM * kD) / (256 * 8), 256, 0, stream>>>(x, xh);
    // 2-3. transpose+cast weights to N x K (pad W_in cols 4192->4224 with zeros)
    transpose_cast_kernel<<<dim3(kLdp / 32, kK / 32), 256, 0, stream>>>(W_in, Wt, kK, kProjW);
    transpose_cast_kernel<<<dim3(kD / 32, kK / 32), 256, 0, stream>>>(W_out, Wot, kK, kD);
    // 4. GEMM1: proj = x @ W_in + b_in (256x128 tiles, 1D swizzled grid)
    gemm_bt_kernel<true><<<(kM / 256) * (kLdp / 128), 256, 0, stream>>>(
        xh, Wt, b_in, kProjW, (void*)projh, kK, kLdp, dtraw);
    // 5. dt / dA
    dt_da_kernel<<<(kB * kH * kL) / 256, 256, 0, stream>>>(dtraw, A_log, dt_bias, dtv, dAv);
    // 6-8. chunked scan (conv fused)
    scan_pass1_kernel<<<kB * kH * kNC, 64, 0, stream>>>(projh, conv_w, conv_b, dtv, dAv, cstate, Pch);
    scan_pass2_kernel<<<kB * kH, 256, 0, stream>>>(cstate, Pch);
    scan_pass3_kernel<<<kB * kH * kNC, 64, 0, stream>>>(projh, conv_w, conv_b, dtv, dAv, cstate, D_param, ypre);
    // 9. gated RMSNorm -> f16
    gated_norm_kernel<<<kM, 256, 0, stream>>>(ypre, projh, norm_w, yh);
    // 10. GEMM2: out = y @ W_out (256x128 tiles)
    gemm_bt_kernel<false><<<(kM / 256) * (kD / 128), 256, 0, stream>>>(
        yh, Wot, nullptr, 0, (void*)out, kK, kD, nullptr);
}